// Round 8
// baseline (445.556 us; speedup 1.0000x reference)
//
#include <hip/hip_runtime.h>
#include <math.h>

#define THREADS 256
#define BSHIFT 8
#define BSIZE 256   // nodes per bucket
#define NEB 512     // edge blocks for hist/place

typedef short short8 __attribute__((ext_vector_type(8)));
typedef float f32x4 __attribute__((ext_vector_type(4)));

// bf16 helpers (storage = ushort; RNE pack, exact unpack)
__device__ __forceinline__ unsigned short f2bf(float f) {
  unsigned u = __builtin_bit_cast(unsigned, f);
  return (unsigned short)((u + 0x7FFFu + ((u >> 16) & 1u)) >> 16);
}
__device__ __forceinline__ float bflo(unsigned u) {
  return __builtin_bit_cast(float, u << 16);
}
__device__ __forceinline__ float bfhi(unsigned u) {
  return __builtin_bit_cast(float, u & 0xFFFF0000u);
}
__device__ __forceinline__ unsigned pack2(float x, float y) {
  return (unsigned)f2bf(x) | ((unsigned)f2bf(y) << 16);
}

// unpack a uint4 (8 bf16 channels) and accumulate into a[0..7]
__device__ __forceinline__ void acc8(float* a, uint4 u) {
  a[0] += bflo(u.x); a[1] += bfhi(u.x);
  a[2] += bflo(u.y); a[3] += bfhi(u.y);
  a[4] += bflo(u.z); a[5] += bfhi(u.z);
  a[6] += bflo(u.w); a[7] += bfhi(u.w);
}

// ---------------- shared agg-one-node body (round-11 proven loop) ----------------
// One node per wave-call: 8 edges/iter, 4 gathers in flight, row-major table
// (4 fully-used 64B lines per edge — R15/R16 proved any split costs 2-3.7x).
// Result written to abrow (LDS row, 132-ushort stride) as bf16.
__device__ __forceinline__ void agg_node(
    const uint2* __restrict__ xlq, const unsigned short* __restrict__ xr,
    const int* __restrict__ row_ptr, const int* __restrict__ col,
    int n, int pair, int l32, unsigned short* abrow) {
  int beg = row_ptr[n], end = row_ptr[n + 1];
  int deg = end - beg;
  float a0x = 0.f, a0y = 0.f, a0z = 0.f, a0w = 0.f;
  float a1x = 0.f, a1y = 0.f, a1z = 0.f, a1w = 0.f;
  float a2x = 0.f, a2y = 0.f, a2z = 0.f, a2w = 0.f;
  float a3x = 0.f, a3y = 0.f, a3z = 0.f, a3w = 0.f;
  int e = beg + pair;
  for (int it = deg >> 3; it > 0; --it, e += 8) {
    uint2 u0 = xlq[(size_t)col[e]     * 32 + l32];
    uint2 u1 = xlq[(size_t)col[e + 2] * 32 + l32];
    uint2 u2 = xlq[(size_t)col[e + 4] * 32 + l32];
    uint2 u3 = xlq[(size_t)col[e + 6] * 32 + l32];
    a0x += bflo(u0.x); a0y += bfhi(u0.x); a0z += bflo(u0.y); a0w += bfhi(u0.y);
    a1x += bflo(u1.x); a1y += bfhi(u1.x); a1z += bflo(u1.y); a1w += bfhi(u1.y);
    a2x += bflo(u2.x); a2y += bfhi(u2.x); a2z += bflo(u2.y); a2w += bfhi(u2.y);
    a3x += bflo(u3.x); a3y += bfhi(u3.x); a3z += bflo(u3.y); a3w += bfhi(u3.y);
  }
  for (; e < end; e += 2) {
    uint2 u = xlq[(size_t)col[e] * 32 + l32];
    a0x += bflo(u.x); a0y += bfhi(u.x); a0z += bflo(u.y); a0w += bfhi(u.y);
  }
  float ax = (a0x + a1x) + (a2x + a3x);
  float ay = (a0y + a1y) + (a2y + a3y);
  float az = (a0z + a1z) + (a2z + a3z);
  float aw = (a0w + a1w) + (a2w + a3w);
  ax += __shfl_xor(ax, 32);
  ay += __shfl_xor(ay, 32);
  az += __shfl_xor(az, 32);
  aw += __shfl_xor(aw, 32);
  if (pair == 0) {
    float di = 1.0f / (float)max(deg, 1);
    uint2 r = ((const uint2*)xr)[(size_t)n * 32 + l32];
    float ox = fmaxf(fmaf(ax, di, bflo(r.x)), 0.f);
    float oy = fmaxf(fmaf(ay, di, bfhi(r.x)), 0.f);
    float oz = fmaxf(fmaf(az, di, bflo(r.y)), 0.f);
    float ow = fmaxf(fmaf(aw, di, bfhi(r.y)), 0.f);
    uint2 o;
    o.x = pack2(ox, oy);
    o.y = pack2(oz, ow);
    *(uint2*)(abrow + l32 * 4) = o;
  }
}

// ---------------- MFMA dual GEMM body, D=128 (LDS-transpose epilogue) ----------------
// lt stride 132 ushorts (264B = 2-bank stride: 2-way conflicts, free per m136).
__device__ __forceinline__ void gemm128_body(
    const short8 xf[4], const short8 xg[4],
    const unsigned short* __restrict__ Wswz, const float* __restrict__ bias,
    unsigned short* __restrict__ outL, unsigned short* __restrict__ outR,
    int M, int lane,
    unsigned short (*lt)[16][132], int rb0) {
  int quad = lane >> 4, n16 = lane & 15;
  // ---- left half (no bias) -> outL ----
#pragma unroll
  for (int ct = 0; ct < 8; ++ct) {
    f32x4 accA = {0.f, 0.f, 0.f, 0.f};
    f32x4 accB = {0.f, 0.f, 0.f, 0.f};
    const unsigned short* wp = Wswz + (size_t)(ct * 64 + lane) * 8;
#pragma unroll
    for (int ks = 0; ks < 4; ++ks) {
      short8 wf = *(const short8*)(wp + ks * 8192);
      accA = __builtin_amdgcn_mfma_f32_16x16x32_bf16(wf, xf[ks], accA, 0, 0, 0);
      accB = __builtin_amdgcn_mfma_f32_16x16x32_bf16(wf, xg[ks], accB, 0, 0, 0);
    }
    int ch = ct * 16 + quad * 4;
    ushort4 oA, oB;
    oA.x = f2bf(accA[0]); oA.y = f2bf(accA[1]); oA.z = f2bf(accA[2]); oA.w = f2bf(accA[3]);
    oB.x = f2bf(accB[0]); oB.y = f2bf(accB[1]); oB.z = f2bf(accB[2]); oB.w = f2bf(accB[3]);
    *(ushort4*)&lt[0][n16][ch] = oA;
    *(ushort4*)&lt[1][n16][ch] = oB;
  }
#pragma unroll
  for (int r = 0; r < 4; ++r) {
    int nd = r * 4 + (lane >> 4);
    int ic = (lane & 15) * 8;
    uint4 vA = *(const uint4*)&lt[0][nd][ic];
    uint4 vB = *(const uint4*)&lt[1][nd][ic];
    if (rb0 + nd < M)      *(uint4*)(outL + ((size_t)(rb0 + nd)) * 128 + ic) = vA;
    if (rb0 + 64 + nd < M) *(uint4*)(outL + ((size_t)(rb0 + 64 + nd)) * 128 + ic) = vB;
  }
  // ---- right half (+bias) -> outR ----
#pragma unroll
  for (int ct = 8; ct < 16; ++ct) {
    f32x4 accA = {0.f, 0.f, 0.f, 0.f};
    f32x4 accB = {0.f, 0.f, 0.f, 0.f};
    const unsigned short* wp = Wswz + (size_t)(ct * 64 + lane) * 8;
#pragma unroll
    for (int ks = 0; ks < 4; ++ks) {
      short8 wf = *(const short8*)(wp + ks * 8192);
      accA = __builtin_amdgcn_mfma_f32_16x16x32_bf16(wf, xf[ks], accA, 0, 0, 0);
      accB = __builtin_amdgcn_mfma_f32_16x16x32_bf16(wf, xg[ks], accB, 0, 0, 0);
    }
    int ch = (ct - 8) * 16 + quad * 4;
    float4 bv = *(const float4*)(bias + ch);
    ushort4 oA, oB;
    oA.x = f2bf(accA[0] + bv.x); oA.y = f2bf(accA[1] + bv.y);
    oA.z = f2bf(accA[2] + bv.z); oA.w = f2bf(accA[3] + bv.w);
    oB.x = f2bf(accB[0] + bv.x); oB.y = f2bf(accB[1] + bv.y);
    oB.z = f2bf(accB[2] + bv.z); oB.w = f2bf(accB[3] + bv.w);
    *(ushort4*)&lt[0][n16][ch] = oA;
    *(ushort4*)&lt[1][n16][ch] = oB;
  }
#pragma unroll
  for (int r = 0; r < 4; ++r) {
    int nd = r * 4 + (lane >> 4);
    int ic = (lane & 15) * 8;
    uint4 vA = *(const uint4*)&lt[0][nd][ic];
    uint4 vB = *(const uint4*)&lt[1][nd][ic];
    if (rb0 + nd < M)      *(uint4*)(outR + ((size_t)(rb0 + nd)) * 128 + ic) = vA;
    if (rb0 + 64 + nd < M) *(uint4*)(outR + ((size_t)(rb0 + 64 + nd)) * 128 + ic) = vB;
  }
}

// ---------------- phase0: edge histogram + all weight swizzles ----------------
__global__ __launch_bounds__(256) void k_phase0(
    const int* __restrict__ dst, int* __restrict__ cnt_bm, int E, int chunk, int nbk,
    const float* __restrict__ Wl0, const float* __restrict__ Wr0,
    const float* __restrict__ Wl1, const float* __restrict__ Wr1,
    const float* __restrict__ Wl2, const float* __restrict__ Wr2,
    unsigned short* __restrict__ out0, unsigned short* __restrict__ out1,
    unsigned short* __restrict__ out2) {
  int b = blockIdx.x, t = threadIdx.x;
  if (b < NEB) {
    __shared__ int h[1024];
    for (int i = t; i < nbk; i += 256) h[i] = 0;
    __syncthreads();
    int e0 = b * chunk, e1 = min(e0 + chunk, E);
    for (int e = e0 + t; e < e1; e += 256) atomicAdd(&h[dst[e] >> BSHIFT], 1);
    __syncthreads();
    for (int i = t; i < nbk; i += 256) cnt_bm[(size_t)b * nbk + i] = h[i];
    return;
  }
  int wb = b - NEB;
  if (wb < 256) {
    const float* Wl = (wb < 128) ? Wl0 : Wl1;
    const float* Wr = (wb < 128) ? Wr0 : Wr1;
    unsigned short* out = (wb < 128) ? out0 : out1;
    int idx = (wb & 127) * 256 + t;  // 0..32767
    int j = idx & 7, lane = (idx >> 3) & 63, ct = (idx >> 9) & 15, ks = idx >> 13;
    int k = ks * 32 + (lane >> 4) * 8 + j;
    int c = ct * 16 + (lane & 15);
    float v = (c < 128) ? Wl[k * 128 + c] : Wr[k * 128 + (c - 128)];
    out[idx] = f2bf(v);
  } else {
    int idx = (wb - 256) * 256 + t;  // 0..10239
    int j = idx & 7, lane = (idx >> 3) & 63;
    int tile = idx >> 9;            // ks*5 + ct
    int ct = tile % 5, ks = tile / 5;
    int k = ks * 32 + (lane >> 4) * 8 + j;
    int c = ct * 16 + (lane & 15);
    float v = (c < 40) ? Wl2[k * 40 + c] : ((c < 80) ? Wr2[k * 40 + (c - 40)] : 0.f);
    out2[idx] = f2bf(v);
  }
}

// ---------------- phase1: bucket scan + layer-0 GEMM (fp32 X in) ----------------
__global__ __launch_bounds__(256) void k_phase1(
    const int* __restrict__ cnt_bm, int* __restrict__ locoff_tm,
    int* __restrict__ bktot, int nbk,
    const float* __restrict__ X, const unsigned short* __restrict__ Wswz,
    const float* __restrict__ bias,
    unsigned short* __restrict__ outL, unsigned short* __restrict__ outR, int M) {
  __shared__ int sh[256];
  __shared__ __align__(16) unsigned short lt[4][2][16][132];
  int t = threadIdx.x;
  if (blockIdx.x < (unsigned)nbk) {
    int g = blockIdx.x;
    int c0 = cnt_bm[(size_t)(2 * t) * nbk + g];
    int c1 = cnt_bm[(size_t)(2 * t + 1) * nbk + g];
    int s = c0 + c1;
    sh[t] = s;
    __syncthreads();
    for (int off = 1; off < 256; off <<= 1) {
      int v = (t >= off) ? sh[t - off] : 0;
      __syncthreads();
      if (t >= off) sh[t] += v;
      __syncthreads();
    }
    int excl = sh[t] - s;
    ((int2*)(locoff_tm + (size_t)g * NEB))[t] = make_int2(excl, excl + c0);
    if (t == 255) bktot[g] = sh[255];
    return;
  }
  int gb = blockIdx.x - nbk;
  int wave = t >> 6, lane = t & 63;
  int quad = lane >> 4, n16 = lane & 15;
  int rowA = gb * 128 + wave * 16 + n16;
  int rA = min(rowA, M - 1), rB = min(rowA + 64, M - 1);

  short8 xf[4], xg[4];
  const float* xpA = X + (size_t)rA * 128 + quad * 8;
  const float* xpB = X + (size_t)rB * 128 + quad * 8;
#pragma unroll
  for (int ks = 0; ks < 4; ++ks) {
    float4 a0 = *(const float4*)(xpA + ks * 32);
    float4 a1 = *(const float4*)(xpA + ks * 32 + 4);
    float4 b0 = *(const float4*)(xpB + ks * 32);
    float4 b1 = *(const float4*)(xpB + ks * 32 + 4);
    short8 f, g;
    f[0] = (short)f2bf(a0.x); f[1] = (short)f2bf(a0.y);
    f[2] = (short)f2bf(a0.z); f[3] = (short)f2bf(a0.w);
    f[4] = (short)f2bf(a1.x); f[5] = (short)f2bf(a1.y);
    f[6] = (short)f2bf(a1.z); f[7] = (short)f2bf(a1.w);
    g[0] = (short)f2bf(b0.x); g[1] = (short)f2bf(b0.y);
    g[2] = (short)f2bf(b0.z); g[3] = (short)f2bf(b0.w);
    g[4] = (short)f2bf(b1.x); g[5] = (short)f2bf(b1.y);
    g[6] = (short)f2bf(b1.z); g[7] = (short)f2bf(b1.w);
    xf[ks] = f;
    xg[ks] = g;
  }
  gemm128_body(xf, xg, Wswz, bias, outL, outR, M, lane,
               lt[wave], gb * 128 + wave * 16);
}

// ---------------- eplace2: in-block top-scan + edge placement ----------------
__global__ __launch_bounds__(256) void k_eplace2(
    const int* __restrict__ src, const int* __restrict__ dst,
    const int* __restrict__ bktot, const int* __restrict__ locoff_tm,
    int* __restrict__ bedge, int* __restrict__ bucket_base,
    int* __restrict__ row_ptr,
    int E, int chunk, int nbk, int N) {
  __shared__ int lptr[1024];
  __shared__ int psum[256];
  int blk = blockIdx.x, t = threadIdx.x;
  int v0 = (2 * t < nbk) ? bktot[2 * t] : 0;
  int v1 = (2 * t + 1 < nbk) ? bktot[2 * t + 1] : 0;
  int s = v0 + v1;
  psum[t] = s;
  __syncthreads();
  for (int off = 1; off < 256; off <<= 1) {
    int v = (t >= off) ? psum[t - off] : 0;
    __syncthreads();
    if (t >= off) psum[t] += v;
    __syncthreads();
  }
  int excl = psum[t] - s;
  if (2 * t < nbk)
    lptr[2 * t] = excl + locoff_tm[(size_t)(2 * t) * NEB + blk];
  if (2 * t + 1 < nbk)
    lptr[2 * t + 1] = excl + v0 + locoff_tm[(size_t)(2 * t + 1) * NEB + blk];
  if (blk == 0) {
    if (2 * t < nbk)     bucket_base[2 * t] = excl;
    if (2 * t + 1 < nbk) bucket_base[2 * t + 1] = excl + v0;
    if (t == 0) { bucket_base[nbk] = E; row_ptr[N] = E; }
  }
  __syncthreads();
  int e0 = blk * chunk, e1 = min(e0 + chunk, E);
  for (int e = e0 + t; e < e1; e += 256) {
    int d = dst[e];
    int bkt = d >> BSHIFT;
    int p = atomicAdd(&lptr[bkt], 1);  // LDS atomic
    bedge[p] = (src[e] << 8) | (d & (BSIZE - 1));
  }
}

__global__ __launch_bounds__(256) void k_bcsr2(const int* __restrict__ bedge,
                                               const int* __restrict__ bucket_base,
                                               int* __restrict__ row_ptr,
                                               int* __restrict__ col, int N) {
  int g = blockIdx.x, t = threadIdx.x;
  int beg = bucket_base[g], end = bucket_base[g + 1];
  __shared__ int deg[BSIZE];
  __shared__ int sh[BSIZE];
  __shared__ int cur[BSIZE];
  deg[t] = 0;
  __syncthreads();
  for (int i = beg + t; i < end; i += 256)
    atomicAdd(&deg[bedge[i] & (BSIZE - 1)], 1);
  __syncthreads();
  int s = deg[t];
  sh[t] = s;
  __syncthreads();
  for (int off = 1; off < 256; off <<= 1) {
    int v = (t >= off) ? sh[t - off] : 0;
    __syncthreads();
    if (t >= off) sh[t] += v;
    __syncthreads();
  }
  int ex = beg + sh[t] - s;
  int node = g * BSIZE + t;
  if (node < N) row_ptr[node] = ex;
  cur[t] = ex;
  __syncthreads();
  for (int i = beg + t; i < end; i += 256) {
    int ed = bedge[i];
    int p = atomicAdd(&cur[ed & (BSIZE - 1)], 1);
    col[p] = ed >> 8;  // value < 2^25, positive
  }
}

// ---------------- fused: layer-0 aggregation + layer-1 GEMM (128ch) ----------------
// R20 occupancy fix of R19's failed fusion (was 68.6KB LDS -> 16 waves/CU,
// occupancy 30%, gather starved): single 33.8KB buffer — ab[128][132] for the
// agg tile, ALIASED by the lt epilogue tile after a second barrier (ab is dead
// once fragments are in registers). 4 blocks/CU x 8 waves = 32 waves/CU.
__global__ __launch_bounds__(512) void k_aggemm128(
    const unsigned short* __restrict__ xl, const unsigned short* __restrict__ xr,
    const int* __restrict__ row_ptr, const int* __restrict__ col,
    const unsigned short* __restrict__ Wswz, const float* __restrict__ bias,
    unsigned short* __restrict__ outL, unsigned short* __restrict__ outR, int Nn) {
  __shared__ __align__(16) unsigned short ab[128][132];  // 33792B, total block LDS
  int wave = threadIdx.x >> 6, lane = threadIdx.x & 63;
  int pair = lane >> 5, l32 = lane & 31;
  int nb0 = blockIdx.x * 128;
  const uint2* xlq = (const uint2*)xl;
#pragma unroll 1
  for (int i = 0; i < 16; ++i) {
    int nl = wave * 16 + i;
    int n = nb0 + nl;
    if (n >= Nn) break;  // uniform per wave
    agg_node(xlq, xr, row_ptr, col, n, pair, l32, &ab[nl][0]);
  }
  __syncthreads();
  // fragment loads (waves 0-3); then ab is dead -> lt may alias it
  short8 xf[4], xg[4];
  if (wave < 4) {
    int quad = lane >> 4, n16 = lane & 15;
    int rowAl = wave * 16 + n16;   // local rows 0..63 / 64..127
#pragma unroll
    for (int ks = 0; ks < 4; ++ks) {
      xf[ks] = *(const short8*)&ab[rowAl][quad * 8 + ks * 32];
      xg[ks] = *(const short8*)&ab[rowAl + 64][quad * 8 + ks * 32];
    }
  }
  __syncthreads();
  if (wave < 4) {
    auto lt4 = (unsigned short (*)[2][16][132]) & ab[0][0];  // 4x8448B = 33792B alias
    gemm128_body(xf, xg, Wswz, bias, outL, outR, Nn, lane,
                 lt4[wave], nb0 + wave * 16);
  }
}

// ---------------- fused: layer-1 aggregation + layer-2 GEMM (40ch) ----------------
// ab[64][132] = 16.9KB -> 8 blocks/CU (32 waves). gemm40 uses direct stores.
__global__ __launch_bounds__(256) void k_aggemm40(
    const unsigned short* __restrict__ xl, const unsigned short* __restrict__ xr,
    const int* __restrict__ row_ptr, const int* __restrict__ col,
    const unsigned short* __restrict__ Wswz, const float* __restrict__ bias,
    unsigned short* __restrict__ tlb, float* __restrict__ tr, int Nn) {
  __shared__ __align__(16) unsigned short ab[64][132];
  int wave = threadIdx.x >> 6, lane = threadIdx.x & 63;
  int pair = lane >> 5, l32 = lane & 31;
  int nb0 = blockIdx.x * 64;
  const uint2* xlq = (const uint2*)xl;
#pragma unroll 1
  for (int i = 0; i < 16; ++i) {
    int nl = wave * 16 + i;
    int n = nb0 + nl;
    if (n >= Nn) break;  // uniform per wave
    agg_node(xlq, xr, row_ptr, col, n, pair, l32, &ab[nl][0]);
  }
  __syncthreads();
  int quad = lane >> 4, n16 = lane & 15;
  int rl = wave * 16 + n16;
  int row = nb0 + rl;
  bool ok = row < Nn;
  short8 xf[4];
#pragma unroll
  for (int ks = 0; ks < 4; ++ks)
    xf[ks] = *(const short8*)&ab[rl][quad * 8 + ks * 32];
#pragma unroll
  for (int ct = 0; ct < 5; ++ct) {
    f32x4 acc = {0.f, 0.f, 0.f, 0.f};
    const unsigned short* wp = Wswz + (size_t)(ct * 64 + lane) * 8;
#pragma unroll
    for (int ks = 0; ks < 4; ++ks) {
      short8 wf = *(const short8*)(wp + (size_t)ks * 5 * 64 * 8);
      acc = __builtin_amdgcn_mfma_f32_16x16x32_bf16(wf, xf[ks], acc, 0, 0, 0);
    }
    int cglob = ct * 16 + quad * 4;
    if (!ok) continue;
    if (cglob < 40) {
      ushort4 o;
      o.x = f2bf(acc[0]); o.y = f2bf(acc[1]); o.z = f2bf(acc[2]); o.w = f2bf(acc[3]);
      *(ushort4*)(tlb + (size_t)row * 40 + cglob) = o;
    } else {
      int c = cglob - 40;
      float4 bv = *(const float4*)(bias + c);
      float4 o;
      o.x = acc[0] + bv.x; o.y = acc[1] + bv.y;
      o.z = acc[2] + bv.z; o.w = acc[3] + bv.w;
      *(float4*)(tr + (size_t)row * 40 + c) = o;
    }
  }
}

// ---------------- aggregation D=40 (packed 80B rows) + log_softmax ----------------
__global__ __launch_bounds__(256) void agg40_lsm(
    const unsigned short* __restrict__ tlb, const float* __restrict__ tr,
    const int* __restrict__ row_ptr, const int* __restrict__ col,
    float* __restrict__ out, int Nn) {
  int wave = threadIdx.x >> 6;
  int lane = threadIdx.x & 63;
  int ew = lane >> 3;    // edge slot 0..7
  int l8 = lane & 7;     // uint4 index; channels 8*l8 .. 8*l8+7
  int n = blockIdx.x * 4 + wave;
  if (n >= Nn) return;
  int beg = row_ptr[n], end = row_ptr[n + 1];
  int deg = end - beg;
  const uint4* tlq = (const uint4*)tlb;
  float a0[8], a1[8];
#pragma unroll
  for (int j = 0; j < 8; ++j) { a0[j] = 0.f; a1[j] = 0.f; }
  int rounds = (deg + 15) >> 4;  // 16 edges per round
  if (rounds > 0) {
    int end1 = end - 1;
    int e = beg + ew;
    int c0 = col[min(e, end1)];
    int c1 = col[min(e + 8, end1)];
    for (int it = rounds - 1; it > 0; --it) {
      uint4 u0 = tlq[(size_t)c0 * 5 + l8];
      uint4 u1 = tlq[(size_t)c1 * 5 + l8];
      int en = e + 16;
      int cn0 = col[min(en, end1)];
      int cn1 = col[min(en + 8, end1)];
      acc8(a0, u0); acc8(a1, u1);
      c0 = cn0; c1 = cn1; e = en;
    }
    uint4 u0 = tlq[(size_t)c0 * 5 + l8];
    uint4 u1 = tlq[(size_t)c1 * 5 + l8];
    uint4 z = make_uint4(0u, 0u, 0u, 0u);
    if (e >= end) u0 = z;
    if (e + 8 >= end) u1 = z;
    acc8(a0, u0); acc8(a1, u1);
  }
  float v[8];
#pragma unroll
  for (int j = 0; j < 8; ++j) {
    float t = a0[j] + a1[j];
    t += __shfl_xor(t, 32);
    t += __shfl_xor(t, 16);
    t += __shfl_xor(t, 8);
    v[j] = t;
  }
  bool valid = l8 < 5;  // channels 8*l8..8*l8+7 < 40
  float di = 1.0f / (float)max(deg, 1);
  float4 r0 = valid ? *(const float4*)(tr + (size_t)n * 40 + 8 * l8)
                    : make_float4(0.f, 0.f, 0.f, 0.f);
  float4 r1 = valid ? *(const float4*)(tr + (size_t)n * 40 + 8 * l8 + 4)
                    : make_float4(0.f, 0.f, 0.f, 0.f);
  float rb[8] = {r0.x, r0.y, r0.z, r0.w, r1.x, r1.y, r1.z, r1.w};
  float vv[8];
#pragma unroll
  for (int j = 0; j < 8; ++j) vv[j] = valid ? fmaf(v[j], di, rb[j]) : -INFINITY;
  float m = vv[0];
#pragma unroll
  for (int j = 1; j < 8; ++j) m = fmaxf(m, vv[j]);
#pragma unroll
  for (int off = 4; off; off >>= 1) m = fmaxf(m, __shfl_xor(m, off));
  float ex = 0.f;
  if (valid) {
#pragma unroll
    for (int j = 0; j < 8; ++j) ex += expf(vv[j] - m);
  }
  float ssum = ex;
#pragma unroll
  for (int off = 4; off; off >>= 1) ssum += __shfl_xor(ssum, off);
  float lg = logf(ssum);
  if (ew == 0 && valid) {
    float4 o0, o1;
    o0.x = (vv[0] - m) - lg; o0.y = (vv[1] - m) - lg;
    o0.z = (vv[2] - m) - lg; o0.w = (vv[3] - m) - lg;
    o1.x = (vv[4] - m) - lg; o1.y = (vv[5] - m) - lg;
    o1.z = (vv[6] - m) - lg; o1.w = (vv[7] - m) - lg;
    *(float4*)(out + (size_t)n * 40 + 8 * l8) = o0;
    *(float4*)(out + (size_t)n * 40 + 8 * l8 + 4) = o1;
  }
}

// ---------------- launcher ----------------

extern "C" void kernel_launch(void* const* d_in, const int* in_sizes, int n_in,
                              void* d_out, int out_size, void* d_ws, size_t ws_size,
                              hipStream_t stream) {
  const float* x   = (const float*)d_in[0];
  const int*   ei  = (const int*)d_in[1];
  const float* Wl0 = (const float*)d_in[2];
  const float* Wr0 = (const float*)d_in[3];
  const float* b0  = (const float*)d_in[4];
  const float* Wl1 = (const float*)d_in[5];
  const float* Wr1 = (const float*)d_in[6];
  const float* b1  = (const float*)d_in[7];
  const float* Wl2 = (const float*)d_in[8];
  const float* Wr2 = (const float*)d_in[9];
  const float* b2  = (const float*)d_in[10];

  int N = in_sizes[0] / 128;
  int E = in_sizes[1] / 2;
  const int* src = ei;
  const int* dst = ei + E;
  int nbk = (N + BSIZE - 1) / BSIZE;       // 391 buckets of 256 nodes
  int chunk = (E + NEB - 1) / NEB;         // edges per hist/place block

  char* ws = (char*)d_ws;
  size_t off = 0;
  auto alloc = [&](size_t bytes) -> void* {
    void* p = ws + off;
    off += (bytes + 255) & ~(size_t)255;
    return p;
  };
  unsigned short* gA  = (unsigned short*)alloc((size_t)N * 128 * 2);  // layer-0 gemm out (L)
  unsigned short* gB  = (unsigned short*)alloc((size_t)N * 128 * 2);  // layer-0 gemm out (R)
  unsigned short* gA2 = (unsigned short*)alloc((size_t)N * 128 * 2);  // layer-1 gemm out (L)
  unsigned short* gB2 = (unsigned short*)alloc((size_t)N * 128 * 2);  // layer-1 gemm out (R)
  int* row_ptr  = (int*)alloc((size_t)(N + 1) * 4);
  int* col      = (int*)alloc((size_t)E * 4);
  int* bedge    = (int*)alloc((size_t)E * 4);   // packed (src<<8)|(dst&255)
  int* cnt_bm   = (int*)alloc((size_t)NEB * nbk * 4);
  int* locoff   = (int*)alloc((size_t)nbk * NEB * 4);
  int* bktot    = (int*)alloc((size_t)nbk * 4);
  int* bbase    = (int*)alloc((size_t)(nbk + 1) * 4);
  unsigned short* wswz0 = (unsigned short*)alloc(32768 * 2);
  unsigned short* wswz1 = (unsigned short*)alloc(32768 * 2);
  unsigned short* wswz2 = (unsigned short*)alloc(10240 * 2);
  // tlb (8MB) + tr (16MB) alias the dead gA region (25.6MB): gA is last read
  // by k_aggemm128, which completes before k_aggemm40 writes tlb/tr.
  unsigned short* tlb = gA;
  float* tr = (float*)((char*)gA + (((size_t)N * 40 * 2 + 255) & ~(size_t)255));
  (void)ws_size; (void)n_in; (void)out_size;

  int gg128 = (N + 127) / 128;
  int nb = (N + 3) / 4;

  // phase0: ehist + all weight swizzles (independent leaves)
  k_phase0<<<NEB + 296, 256, 0, stream>>>(dst, cnt_bm, E, chunk, nbk,
                                          Wl0, Wr0, Wl1, Wr1, Wl2, Wr2,
                                          wswz0, wswz1, wswz2);
  // phase1: bucket scans + layer-0 GEMM (overlapped, independent)
  k_phase1<<<nbk + gg128, 256, 0, stream>>>(cnt_bm, locoff, bktot, nbk,
                                            x, wswz0, b0, gA, gB, N);
  // edge placement (with in-block top-scan)
  k_eplace2<<<NEB, 256, 0, stream>>>(src, dst, bktot, locoff, bedge, bbase,
                                     row_ptr, E, chunk, nbk, N);
  k_bcsr2<<<nbk, 256, 0, stream>>>(bedge, bbase, row_ptr, col, N);

  // layer-0 agg + layer-1 gemm (fused through LDS; hC eliminated)
  k_aggemm128<<<gg128, 512, 0, stream>>>(gA, gB, row_ptr, col,
                                         wswz1, b1, gA2, gB2, N);
  // layer-1 agg + layer-2 gemm40 (fused through LDS)
  k_aggemm40<<<(N + 63) / 64, 256, 0, stream>>>(gA2, gB2, row_ptr, col,
                                                wswz2, b2, tlb, tr, N);
  // final aggregation + log_softmax
  agg40_lsm<<<nb, 256, 0, stream>>>(tlb, tr, row_ptr, col, (float*)d_out, N);
}

// Round 9
// 393.729 us; speedup vs baseline: 1.1316x; 1.1316x over previous
//
#include <hip/hip_runtime.h>
#include <math.h>

#define THREADS 256
#define BSHIFT 8
#define BSIZE 256   // nodes per bucket
#define NEB 512     // edge blocks for hist/place

typedef short short8 __attribute__((ext_vector_type(8)));
typedef float f32x4 __attribute__((ext_vector_type(4)));

// bf16 helpers (storage = ushort; RNE pack, exact unpack)
__device__ __forceinline__ unsigned short f2bf(float f) {
  unsigned u = __builtin_bit_cast(unsigned, f);
  return (unsigned short)((u + 0x7FFFu + ((u >> 16) & 1u)) >> 16);
}
__device__ __forceinline__ float bflo(unsigned u) {
  return __builtin_bit_cast(float, u << 16);
}
__device__ __forceinline__ float bfhi(unsigned u) {
  return __builtin_bit_cast(float, u & 0xFFFF0000u);
}
__device__ __forceinline__ unsigned pack2(float x, float y) {
  return (unsigned)f2bf(x) | ((unsigned)f2bf(y) << 16);
}

// unpack a uint4 (8 bf16 channels) and accumulate into a[0..7]
__device__ __forceinline__ void acc8(float* a, uint4 u) {
  a[0] += bflo(u.x); a[1] += bfhi(u.x);
  a[2] += bflo(u.y); a[3] += bfhi(u.y);
  a[4] += bflo(u.z); a[5] += bfhi(u.z);
  a[6] += bflo(u.w); a[7] += bfhi(u.w);
}

// ---------------- shared agg-one-node body (round-11 proven loop) ----------------
// One node per wave-call: 8 edges/iter, 4 gathers in flight, row-major table
// (4 fully-used 64B lines per edge — R15/R16 proved any split costs 2-3.7x).
__device__ __forceinline__ void agg_node(
    const uint2* __restrict__ xlq, const unsigned short* __restrict__ xr,
    const int* __restrict__ row_ptr, const int* __restrict__ col,
    int n, int pair, int l32, unsigned short* abrow) {
  int beg = row_ptr[n], end = row_ptr[n + 1];
  int deg = end - beg;
  float a0x = 0.f, a0y = 0.f, a0z = 0.f, a0w = 0.f;
  float a1x = 0.f, a1y = 0.f, a1z = 0.f, a1w = 0.f;
  float a2x = 0.f, a2y = 0.f, a2z = 0.f, a2w = 0.f;
  float a3x = 0.f, a3y = 0.f, a3z = 0.f, a3w = 0.f;
  int e = beg + pair;
  for (int it = deg >> 3; it > 0; --it, e += 8) {
    uint2 u0 = xlq[(size_t)col[e]     * 32 + l32];
    uint2 u1 = xlq[(size_t)col[e + 2] * 32 + l32];
    uint2 u2 = xlq[(size_t)col[e + 4] * 32 + l32];
    uint2 u3 = xlq[(size_t)col[e + 6] * 32 + l32];
    a0x += bflo(u0.x); a0y += bfhi(u0.x); a0z += bflo(u0.y); a0w += bfhi(u0.y);
    a1x += bflo(u1.x); a1y += bfhi(u1.x); a1z += bflo(u1.y); a1w += bfhi(u1.y);
    a2x += bflo(u2.x); a2y += bfhi(u2.x); a2z += bflo(u2.y); a2w += bfhi(u2.y);
    a3x += bflo(u3.x); a3y += bfhi(u3.x); a3z += bflo(u3.y); a3w += bfhi(u3.y);
  }
  for (; e < end; e += 2) {
    uint2 u = xlq[(size_t)col[e] * 32 + l32];
    a0x += bflo(u.x); a0y += bfhi(u.x); a0z += bflo(u.y); a0w += bfhi(u.y);
  }
  float ax = (a0x + a1x) + (a2x + a3x);
  float ay = (a0y + a1y) + (a2y + a3y);
  float az = (a0z + a1z) + (a2z + a3z);
  float aw = (a0w + a1w) + (a2w + a3w);
  ax += __shfl_xor(ax, 32);
  ay += __shfl_xor(ay, 32);
  az += __shfl_xor(az, 32);
  aw += __shfl_xor(aw, 32);
  if (pair == 0) {
    float di = 1.0f / (float)max(deg, 1);
    uint2 r = ((const uint2*)xr)[(size_t)n * 32 + l32];
    float ox = fmaxf(fmaf(ax, di, bflo(r.x)), 0.f);
    float oy = fmaxf(fmaf(ay, di, bfhi(r.x)), 0.f);
    float oz = fmaxf(fmaf(az, di, bflo(r.y)), 0.f);
    float ow = fmaxf(fmaf(aw, di, bfhi(r.y)), 0.f);
    uint2 o;
    o.x = pack2(ox, oy);
    o.y = pack2(oz, ow);
    *(uint2*)(abrow + l32 * 4) = o;
  }
}

// ---------------- MFMA dual GEMM body, D=128 (LDS-transpose epilogue) ----------------
__device__ __forceinline__ void gemm128_body(
    const short8 xf[4], const short8 xg[4],
    const unsigned short* __restrict__ Wswz, const float* __restrict__ bias,
    unsigned short* __restrict__ outL, unsigned short* __restrict__ outR,
    int M, int lane,
    unsigned short (*lt)[16][132], int rb0) {
  int quad = lane >> 4, n16 = lane & 15;
  // ---- left half (no bias) -> outL ----
#pragma unroll
  for (int ct = 0; ct < 8; ++ct) {
    f32x4 accA = {0.f, 0.f, 0.f, 0.f};
    f32x4 accB = {0.f, 0.f, 0.f, 0.f};
    const unsigned short* wp = Wswz + (size_t)(ct * 64 + lane) * 8;
#pragma unroll
    for (int ks = 0; ks < 4; ++ks) {
      short8 wf = *(const short8*)(wp + ks * 8192);
      accA = __builtin_amdgcn_mfma_f32_16x16x32_bf16(wf, xf[ks], accA, 0, 0, 0);
      accB = __builtin_amdgcn_mfma_f32_16x16x32_bf16(wf, xg[ks], accB, 0, 0, 0);
    }
    int ch = ct * 16 + quad * 4;
    ushort4 oA, oB;
    oA.x = f2bf(accA[0]); oA.y = f2bf(accA[1]); oA.z = f2bf(accA[2]); oA.w = f2bf(accA[3]);
    oB.x = f2bf(accB[0]); oB.y = f2bf(accB[1]); oB.z = f2bf(accB[2]); oB.w = f2bf(accB[3]);
    *(ushort4*)&lt[0][n16][ch] = oA;
    *(ushort4*)&lt[1][n16][ch] = oB;
  }
#pragma unroll
  for (int r = 0; r < 4; ++r) {
    int nd = r * 4 + (lane >> 4);
    int ic = (lane & 15) * 8;
    uint4 vA = *(const uint4*)&lt[0][nd][ic];
    uint4 vB = *(const uint4*)&lt[1][nd][ic];
    if (rb0 + nd < M)      *(uint4*)(outL + ((size_t)(rb0 + nd)) * 128 + ic) = vA;
    if (rb0 + 64 + nd < M) *(uint4*)(outL + ((size_t)(rb0 + 64 + nd)) * 128 + ic) = vB;
  }
  // ---- right half (+bias) -> outR ----
#pragma unroll
  for (int ct = 8; ct < 16; ++ct) {
    f32x4 accA = {0.f, 0.f, 0.f, 0.f};
    f32x4 accB = {0.f, 0.f, 0.f, 0.f};
    const unsigned short* wp = Wswz + (size_t)(ct * 64 + lane) * 8;
#pragma unroll
    for (int ks = 0; ks < 4; ++ks) {
      short8 wf = *(const short8*)(wp + ks * 8192);
      accA = __builtin_amdgcn_mfma_f32_16x16x32_bf16(wf, xf[ks], accA, 0, 0, 0);
      accB = __builtin_amdgcn_mfma_f32_16x16x32_bf16(wf, xg[ks], accB, 0, 0, 0);
    }
    int ch = (ct - 8) * 16 + quad * 4;
    float4 bv = *(const float4*)(bias + ch);
    ushort4 oA, oB;
    oA.x = f2bf(accA[0] + bv.x); oA.y = f2bf(accA[1] + bv.y);
    oA.z = f2bf(accA[2] + bv.z); oA.w = f2bf(accA[3] + bv.w);
    oB.x = f2bf(accB[0] + bv.x); oB.y = f2bf(accB[1] + bv.y);
    oB.z = f2bf(accB[2] + bv.z); oB.w = f2bf(accB[3] + bv.w);
    *(ushort4*)&lt[0][n16][ch] = oA;
    *(ushort4*)&lt[1][n16][ch] = oB;
  }
#pragma unroll
  for (int r = 0; r < 4; ++r) {
    int nd = r * 4 + (lane >> 4);
    int ic = (lane & 15) * 8;
    uint4 vA = *(const uint4*)&lt[0][nd][ic];
    uint4 vB = *(const uint4*)&lt[1][nd][ic];
    if (rb0 + nd < M)      *(uint4*)(outR + ((size_t)(rb0 + nd)) * 128 + ic) = vA;
    if (rb0 + 64 + nd < M) *(uint4*)(outR + ((size_t)(rb0 + 64 + nd)) * 128 + ic) = vB;
  }
}

// ---------------- phase0: edge histogram + all weight swizzles ----------------
__global__ __launch_bounds__(256) void k_phase0(
    const int* __restrict__ dst, int* __restrict__ cnt_bm, int E, int chunk, int nbk,
    const float* __restrict__ Wl0, const float* __restrict__ Wr0,
    const float* __restrict__ Wl1, const float* __restrict__ Wr1,
    const float* __restrict__ Wl2, const float* __restrict__ Wr2,
    unsigned short* __restrict__ out0, unsigned short* __restrict__ out1,
    unsigned short* __restrict__ out2) {
  int b = blockIdx.x, t = threadIdx.x;
  if (b < NEB) {
    __shared__ int h[1024];
    for (int i = t; i < nbk; i += 256) h[i] = 0;
    __syncthreads();
    int e0 = b * chunk, e1 = min(e0 + chunk, E);
    for (int e = e0 + t; e < e1; e += 256) atomicAdd(&h[dst[e] >> BSHIFT], 1);
    __syncthreads();
    for (int i = t; i < nbk; i += 256) cnt_bm[(size_t)b * nbk + i] = h[i];
    return;
  }
  int wb = b - NEB;
  if (wb < 256) {
    const float* Wl = (wb < 128) ? Wl0 : Wl1;
    const float* Wr = (wb < 128) ? Wr0 : Wr1;
    unsigned short* out = (wb < 128) ? out0 : out1;
    int idx = (wb & 127) * 256 + t;  // 0..32767
    int j = idx & 7, lane = (idx >> 3) & 63, ct = (idx >> 9) & 15, ks = idx >> 13;
    int k = ks * 32 + (lane >> 4) * 8 + j;
    int c = ct * 16 + (lane & 15);
    float v = (c < 128) ? Wl[k * 128 + c] : Wr[k * 128 + (c - 128)];
    out[idx] = f2bf(v);
  } else {
    int idx = (wb - 256) * 256 + t;  // 0..10239
    int j = idx & 7, lane = (idx >> 3) & 63;
    int tile = idx >> 9;            // ks*5 + ct
    int ct = tile % 5, ks = tile / 5;
    int k = ks * 32 + (lane >> 4) * 8 + j;
    int c = ct * 16 + (lane & 15);
    float v = (c < 40) ? Wl2[k * 40 + c] : ((c < 80) ? Wr2[k * 40 + (c - 40)] : 0.f);
    out2[idx] = f2bf(v);
  }
}

// ---------------- phase1: bucket scan + layer-0 GEMM (fp32 X in) ----------------
__global__ __launch_bounds__(256) void k_phase1(
    const int* __restrict__ cnt_bm, int* __restrict__ locoff_tm,
    int* __restrict__ bktot, int nbk,
    const float* __restrict__ X, const unsigned short* __restrict__ Wswz,
    const float* __restrict__ bias,
    unsigned short* __restrict__ outL, unsigned short* __restrict__ outR, int M) {
  __shared__ int sh[256];
  __shared__ __align__(16) unsigned short lt[4][2][16][132];
  int t = threadIdx.x;
  if (blockIdx.x < (unsigned)nbk) {
    int g = blockIdx.x;
    int c0 = cnt_bm[(size_t)(2 * t) * nbk + g];
    int c1 = cnt_bm[(size_t)(2 * t + 1) * nbk + g];
    int s = c0 + c1;
    sh[t] = s;
    __syncthreads();
    for (int off = 1; off < 256; off <<= 1) {
      int v = (t >= off) ? sh[t - off] : 0;
      __syncthreads();
      if (t >= off) sh[t] += v;
      __syncthreads();
    }
    int excl = sh[t] - s;
    ((int2*)(locoff_tm + (size_t)g * NEB))[t] = make_int2(excl, excl + c0);
    if (t == 255) bktot[g] = sh[255];
    return;
  }
  int gb = blockIdx.x - nbk;
  int wave = t >> 6, lane = t & 63;
  int quad = lane >> 4, n16 = lane & 15;
  int rowA = gb * 128 + wave * 16 + n16;
  int rA = min(rowA, M - 1), rB = min(rowA + 64, M - 1);

  short8 xf[4], xg[4];
  const float* xpA = X + (size_t)rA * 128 + quad * 8;
  const float* xpB = X + (size_t)rB * 128 + quad * 8;
#pragma unroll
  for (int ks = 0; ks < 4; ++ks) {
    float4 a0 = *(const float4*)(xpA + ks * 32);
    float4 a1 = *(const float4*)(xpA + ks * 32 + 4);
    float4 b0 = *(const float4*)(xpB + ks * 32);
    float4 b1 = *(const float4*)(xpB + ks * 32 + 4);
    short8 f, g;
    f[0] = (short)f2bf(a0.x); f[1] = (short)f2bf(a0.y);
    f[2] = (short)f2bf(a0.z); f[3] = (short)f2bf(a0.w);
    f[4] = (short)f2bf(a1.x); f[5] = (short)f2bf(a1.y);
    f[6] = (short)f2bf(a1.z); f[7] = (short)f2bf(a1.w);
    g[0] = (short)f2bf(b0.x); g[1] = (short)f2bf(b0.y);
    g[2] = (short)f2bf(b0.z); g[3] = (short)f2bf(b0.w);
    g[4] = (short)f2bf(b1.x); g[5] = (short)f2bf(b1.y);
    g[6] = (short)f2bf(b1.z); g[7] = (short)f2bf(b1.w);
    xf[ks] = f;
    xg[ks] = g;
  }
  gemm128_body(xf, xg, Wswz, bias, outL, outR, M, lane,
               lt[wave], gb * 128 + wave * 16);
}

// ---------------- eplace2: in-block top-scan + edge placement ----------------
__global__ __launch_bounds__(256) void k_eplace2(
    const int* __restrict__ src, const int* __restrict__ dst,
    const int* __restrict__ bktot, const int* __restrict__ locoff_tm,
    int* __restrict__ bedge, int* __restrict__ bucket_base,
    int* __restrict__ row_ptr,
    int E, int chunk, int nbk, int N) {
  __shared__ int lptr[1024];
  __shared__ int psum[256];
  int blk = blockIdx.x, t = threadIdx.x;
  int v0 = (2 * t < nbk) ? bktot[2 * t] : 0;
  int v1 = (2 * t + 1 < nbk) ? bktot[2 * t + 1] : 0;
  int s = v0 + v1;
  psum[t] = s;
  __syncthreads();
  for (int off = 1; off < 256; off <<= 1) {
    int v = (t >= off) ? psum[t - off] : 0;
    __syncthreads();
    if (t >= off) psum[t] += v;
    __syncthreads();
  }
  int excl = psum[t] - s;
  if (2 * t < nbk)
    lptr[2 * t] = excl + locoff_tm[(size_t)(2 * t) * NEB + blk];
  if (2 * t + 1 < nbk)
    lptr[2 * t + 1] = excl + v0 + locoff_tm[(size_t)(2 * t + 1) * NEB + blk];
  if (blk == 0) {
    if (2 * t < nbk)     bucket_base[2 * t] = excl;
    if (2 * t + 1 < nbk) bucket_base[2 * t + 1] = excl + v0;
    if (t == 0) { bucket_base[nbk] = E; row_ptr[N] = E; }
  }
  __syncthreads();
  int e0 = blk * chunk, e1 = min(e0 + chunk, E);
  for (int e = e0 + t; e < e1; e += 256) {
    int d = dst[e];
    int bkt = d >> BSHIFT;
    int p = atomicAdd(&lptr[bkt], 1);  // LDS atomic
    bedge[p] = (src[e] << 8) | (d & (BSIZE - 1));
  }
}

__global__ __launch_bounds__(256) void k_bcsr2(const int* __restrict__ bedge,
                                               const int* __restrict__ bucket_base,
                                               int* __restrict__ row_ptr,
                                               int* __restrict__ col, int N) {
  int g = blockIdx.x, t = threadIdx.x;
  int beg = bucket_base[g], end = bucket_base[g + 1];
  __shared__ int deg[BSIZE];
  __shared__ int sh[BSIZE];
  __shared__ int cur[BSIZE];
  deg[t] = 0;
  __syncthreads();
  for (int i = beg + t; i < end; i += 256)
    atomicAdd(&deg[bedge[i] & (BSIZE - 1)], 1);
  __syncthreads();
  int s = deg[t];
  sh[t] = s;
  __syncthreads();
  for (int off = 1; off < 256; off <<= 1) {
    int v = (t >= off) ? sh[t - off] : 0;
    __syncthreads();
    if (t >= off) sh[t] += v;
    __syncthreads();
  }
  int ex = beg + sh[t] - s;
  int node = g * BSIZE + t;
  if (node < N) row_ptr[node] = ex;
  cur[t] = ex;
  __syncthreads();
  for (int i = beg + t; i < end; i += 256) {
    int ed = bedge[i];
    int p = atomicAdd(&cur[ed & (BSIZE - 1)], 1);
    col[p] = ed >> 8;  // value < 2^25, positive
  }
}

// ---------------- aggregation D=128 (bf16), fused deg_inv+add+relu ----------------
// Round-11 proven form, standalone (R19/R20 proved fusing this with the
// 128-ch GEMM is structurally bad: 512-thr barrier coupling pins occupancy
// at 30% regardless of LDS, +48us). One node/wave, 8 edges/iter, 28 VGPR.
__global__ __launch_bounds__(256) void agg128b(
    const unsigned short* __restrict__ xl, const unsigned short* __restrict__ xr,
    const int* __restrict__ row_ptr, const int* __restrict__ col,
    unsigned short* __restrict__ h, int Nn) {
  int wave = threadIdx.x >> 6;
  int lane = threadIdx.x & 63;
  int pair = lane >> 5;
  int l32 = lane & 31;
  int n = blockIdx.x * 4 + wave;
  if (n >= Nn) return;
  int beg = row_ptr[n], end = row_ptr[n + 1];
  int deg = end - beg;
  const uint2* xlq = (const uint2*)xl;
  float a0x = 0.f, a0y = 0.f, a0z = 0.f, a0w = 0.f;
  float a1x = 0.f, a1y = 0.f, a1z = 0.f, a1w = 0.f;
  float a2x = 0.f, a2y = 0.f, a2z = 0.f, a2w = 0.f;
  float a3x = 0.f, a3y = 0.f, a3z = 0.f, a3w = 0.f;
  int e = beg + pair;
  for (int it = deg >> 3; it > 0; --it, e += 8) {
    uint2 u0 = xlq[(size_t)col[e]     * 32 + l32];
    uint2 u1 = xlq[(size_t)col[e + 2] * 32 + l32];
    uint2 u2 = xlq[(size_t)col[e + 4] * 32 + l32];
    uint2 u3 = xlq[(size_t)col[e + 6] * 32 + l32];
    a0x += bflo(u0.x); a0y += bfhi(u0.x); a0z += bflo(u0.y); a0w += bfhi(u0.y);
    a1x += bflo(u1.x); a1y += bfhi(u1.x); a1z += bflo(u1.y); a1w += bfhi(u1.y);
    a2x += bflo(u2.x); a2y += bfhi(u2.x); a2z += bflo(u2.y); a2w += bfhi(u2.y);
    a3x += bflo(u3.x); a3y += bfhi(u3.x); a3z += bflo(u3.y); a3w += bfhi(u3.y);
  }
  for (; e < end; e += 2) {
    uint2 u = xlq[(size_t)col[e] * 32 + l32];
    a0x += bflo(u.x); a0y += bfhi(u.x); a0z += bflo(u.y); a0w += bfhi(u.y);
  }
  float ax = (a0x + a1x) + (a2x + a3x);
  float ay = (a0y + a1y) + (a2y + a3y);
  float az = (a0z + a1z) + (a2z + a3z);
  float aw = (a0w + a1w) + (a2w + a3w);
  ax += __shfl_xor(ax, 32);
  ay += __shfl_xor(ay, 32);
  az += __shfl_xor(az, 32);
  aw += __shfl_xor(aw, 32);
  if (pair == 0) {
    float di = 1.0f / (float)max(deg, 1);
    uint2 r = ((const uint2*)xr)[(size_t)n * 32 + l32];
    float ox = fmaxf(fmaf(ax, di, bflo(r.x)), 0.f);
    float oy = fmaxf(fmaf(ay, di, bfhi(r.x)), 0.f);
    float oz = fmaxf(fmaf(az, di, bflo(r.y)), 0.f);
    float ow = fmaxf(fmaf(aw, di, bfhi(r.y)), 0.f);
    uint2 o;
    o.x = pack2(ox, oy);
    o.y = pack2(oz, ow);
    ((uint2*)h)[(size_t)n * 32 + l32] = o;
  }
}

// ---------------- MFMA dual GEMM, D=128, bf16 in (layer 1) ----------------
__global__ __launch_bounds__(256) void gemm128_mfma(
    const unsigned short* __restrict__ Xb, const unsigned short* __restrict__ Wswz,
    const float* __restrict__ bias,
    unsigned short* __restrict__ outL, unsigned short* __restrict__ outR, int M) {
  __shared__ __align__(16) unsigned short lt[4][2][16][132];
  int wave = threadIdx.x >> 6, lane = threadIdx.x & 63;
  int quad = lane >> 4, n16 = lane & 15;
  int rowA = blockIdx.x * 128 + wave * 16 + n16;
  int rA = min(rowA, M - 1), rB = min(rowA + 64, M - 1);

  short8 xf[4], xg[4];
  const unsigned short* xpA = Xb + (size_t)rA * 128 + quad * 8;
  const unsigned short* xpB = Xb + (size_t)rB * 128 + quad * 8;
#pragma unroll
  for (int ks = 0; ks < 4; ++ks) {
    xf[ks] = *(const short8*)(xpA + ks * 32);
    xg[ks] = *(const short8*)(xpB + ks * 32);
  }
  gemm128_body(xf, xg, Wswz, bias, outL, outR, M, lane,
               lt[wave], blockIdx.x * 128 + wave * 16);
}

// ---------------- fused: layer-1 aggregation + layer-2 GEMM (40ch) ----------------
// Kept from R19/R20: measured ~73us vs 76 split (256-thr/16.9KB keeps 8
// blocks x 4 waves = 32 waves/CU; no occupancy pathology), saves a launch.
__global__ __launch_bounds__(256) void k_aggemm40(
    const unsigned short* __restrict__ xl, const unsigned short* __restrict__ xr,
    const int* __restrict__ row_ptr, const int* __restrict__ col,
    const unsigned short* __restrict__ Wswz, const float* __restrict__ bias,
    unsigned short* __restrict__ tlb, float* __restrict__ tr, int Nn) {
  __shared__ __align__(16) unsigned short ab[64][132];
  int wave = threadIdx.x >> 6, lane = threadIdx.x & 63;
  int pair = lane >> 5, l32 = lane & 31;
  int nb0 = blockIdx.x * 64;
  const uint2* xlq = (const uint2*)xl;
#pragma unroll 1
  for (int i = 0; i < 16; ++i) {
    int nl = wave * 16 + i;
    int n = nb0 + nl;
    if (n >= Nn) break;  // uniform per wave
    agg_node(xlq, xr, row_ptr, col, n, pair, l32, &ab[nl][0]);
  }
  __syncthreads();
  int quad = lane >> 4, n16 = lane & 15;
  int rl = wave * 16 + n16;
  int row = nb0 + rl;
  bool ok = row < Nn;
  short8 xf[4];
#pragma unroll
  for (int ks = 0; ks < 4; ++ks)
    xf[ks] = *(const short8*)&ab[rl][quad * 8 + ks * 32];
#pragma unroll
  for (int ct = 0; ct < 5; ++ct) {
    f32x4 acc = {0.f, 0.f, 0.f, 0.f};
    const unsigned short* wp = Wswz + (size_t)(ct * 64 + lane) * 8;
#pragma unroll
    for (int ks = 0; ks < 4; ++ks) {
      short8 wf = *(const short8*)(wp + (size_t)ks * 5 * 64 * 8);
      acc = __builtin_amdgcn_mfma_f32_16x16x32_bf16(wf, xf[ks], acc, 0, 0, 0);
    }
    int cglob = ct * 16 + quad * 4;
    if (!ok) continue;
    if (cglob < 40) {
      ushort4 o;
      o.x = f2bf(acc[0]); o.y = f2bf(acc[1]); o.z = f2bf(acc[2]); o.w = f2bf(acc[3]);
      *(ushort4*)(tlb + (size_t)row * 40 + cglob) = o;
    } else {
      int c = cglob - 40;
      float4 bv = *(const float4*)(bias + c);
      float4 o;
      o.x = acc[0] + bv.x; o.y = acc[1] + bv.y;
      o.z = acc[2] + bv.z; o.w = acc[3] + bv.w;
      *(float4*)(tr + (size_t)row * 40 + c) = o;
    }
  }
}

// ---------------- aggregation D=40 (packed 80B rows) + log_softmax ----------------
__global__ __launch_bounds__(256) void agg40_lsm(
    const unsigned short* __restrict__ tlb, const float* __restrict__ tr,
    const int* __restrict__ row_ptr, const int* __restrict__ col,
    float* __restrict__ out, int Nn) {
  int wave = threadIdx.x >> 6;
  int lane = threadIdx.x & 63;
  int ew = lane >> 3;    // edge slot 0..7
  int l8 = lane & 7;     // uint4 index; channels 8*l8 .. 8*l8+7
  int n = blockIdx.x * 4 + wave;
  if (n >= Nn) return;
  int beg = row_ptr[n], end = row_ptr[n + 1];
  int deg = end - beg;
  const uint4* tlq = (const uint4*)tlb;
  float a0[8], a1[8];
#pragma unroll
  for (int j = 0; j < 8; ++j) { a0[j] = 0.f; a1[j] = 0.f; }
  int rounds = (deg + 15) >> 4;  // 16 edges per round
  if (rounds > 0) {
    int end1 = end - 1;
    int e = beg + ew;
    int c0 = col[min(e, end1)];
    int c1 = col[min(e + 8, end1)];
    for (int it = rounds - 1; it > 0; --it) {
      uint4 u0 = tlq[(size_t)c0 * 5 + l8];
      uint4 u1 = tlq[(size_t)c1 * 5 + l8];
      int en = e + 16;
      int cn0 = col[min(en, end1)];
      int cn1 = col[min(en + 8, end1)];
      acc8(a0, u0); acc8(a1, u1);
      c0 = cn0; c1 = cn1; e = en;
    }
    uint4 u0 = tlq[(size_t)c0 * 5 + l8];
    uint4 u1 = tlq[(size_t)c1 * 5 + l8];
    uint4 z = make_uint4(0u, 0u, 0u, 0u);
    if (e >= end) u0 = z;
    if (e + 8 >= end) u1 = z;
    acc8(a0, u0); acc8(a1, u1);
  }
  float v[8];
#pragma unroll
  for (int j = 0; j < 8; ++j) {
    float t = a0[j] + a1[j];
    t += __shfl_xor(t, 32);
    t += __shfl_xor(t, 16);
    t += __shfl_xor(t, 8);
    v[j] = t;
  }
  bool valid = l8 < 5;  // channels 8*l8..8*l8+7 < 40
  float di = 1.0f / (float)max(deg, 1);
  float4 r0 = valid ? *(const float4*)(tr + (size_t)n * 40 + 8 * l8)
                    : make_float4(0.f, 0.f, 0.f, 0.f);
  float4 r1 = valid ? *(const float4*)(tr + (size_t)n * 40 + 8 * l8 + 4)
                    : make_float4(0.f, 0.f, 0.f, 0.f);
  float rb[8] = {r0.x, r0.y, r0.z, r0.w, r1.x, r1.y, r1.z, r1.w};
  float vv[8];
#pragma unroll
  for (int j = 0; j < 8; ++j) vv[j] = valid ? fmaf(v[j], di, rb[j]) : -INFINITY;
  float m = vv[0];
#pragma unroll
  for (int j = 1; j < 8; ++j) m = fmaxf(m, vv[j]);
#pragma unroll
  for (int off = 4; off; off >>= 1) m = fmaxf(m, __shfl_xor(m, off));
  float ex = 0.f;
  if (valid) {
#pragma unroll
    for (int j = 0; j < 8; ++j) ex += expf(vv[j] - m);
  }
  float ssum = ex;
#pragma unroll
  for (int off = 4; off; off >>= 1) ssum += __shfl_xor(ssum, off);
  float lg = logf(ssum);
  if (ew == 0 && valid) {
    float4 o0, o1;
    o0.x = (vv[0] - m) - lg; o0.y = (vv[1] - m) - lg;
    o0.z = (vv[2] - m) - lg; o0.w = (vv[3] - m) - lg;
    o1.x = (vv[4] - m) - lg; o1.y = (vv[5] - m) - lg;
    o1.z = (vv[6] - m) - lg; o1.w = (vv[7] - m) - lg;
    *(float4*)(out + (size_t)n * 40 + 8 * l8) = o0;
    *(float4*)(out + (size_t)n * 40 + 8 * l8 + 4) = o1;
  }
}

// ---------------- launcher ----------------

extern "C" void kernel_launch(void* const* d_in, const int* in_sizes, int n_in,
                              void* d_out, int out_size, void* d_ws, size_t ws_size,
                              hipStream_t stream) {
  const float* x   = (const float*)d_in[0];
  const int*   ei  = (const int*)d_in[1];
  const float* Wl0 = (const float*)d_in[2];
  const float* Wr0 = (const float*)d_in[3];
  const float* b0  = (const float*)d_in[4];
  const float* Wl1 = (const float*)d_in[5];
  const float* Wr1 = (const float*)d_in[6];
  const float* b1  = (const float*)d_in[7];
  const float* Wl2 = (const float*)d_in[8];
  const float* Wr2 = (const float*)d_in[9];
  const float* b2  = (const float*)d_in[10];

  int N = in_sizes[0] / 128;
  int E = in_sizes[1] / 2;
  const int* src = ei;
  const int* dst = ei + E;
  int nbk = (N + BSIZE - 1) / BSIZE;       // 391 buckets of 256 nodes
  int chunk = (E + NEB - 1) / NEB;         // edges per hist/place block

  char* ws = (char*)d_ws;
  size_t off = 0;
  auto alloc = [&](size_t bytes) -> void* {
    void* p = ws + off;
    off += (bytes + 255) & ~(size_t)255;
    return p;
  };
  unsigned short* gA  = (unsigned short*)alloc((size_t)N * 128 * 2);  // gemm L out (reused)
  unsigned short* gB  = (unsigned short*)alloc((size_t)N * 128 * 2);  // gemm R out (reused)
  unsigned short* hC  = (unsigned short*)alloc((size_t)N * 128 * 2);  // agg#1 out / tlb+tr alias
  int* row_ptr  = (int*)alloc((size_t)(N + 1) * 4);
  int* col      = (int*)alloc((size_t)E * 4);
  int* bedge    = (int*)alloc((size_t)E * 4);   // packed (src<<8)|(dst&255)
  int* cnt_bm   = (int*)alloc((size_t)NEB * nbk * 4);
  int* locoff   = (int*)alloc((size_t)nbk * NEB * 4);
  int* bktot    = (int*)alloc((size_t)nbk * 4);
  int* bbase    = (int*)alloc((size_t)(nbk + 1) * 4);
  unsigned short* wswz0 = (unsigned short*)alloc(32768 * 2);
  unsigned short* wswz1 = (unsigned short*)alloc(32768 * 2);
  unsigned short* wswz2 = (unsigned short*)alloc(10240 * 2);
  // tlb (8MB) + tr (16MB) alias hC (25.6MB): hC is last read by gemm128_mfma,
  // which completes before k_aggemm40 writes tlb/tr (kernel-boundary order).
  unsigned short* tlb = hC;
  float* tr = (float*)((char*)hC + (((size_t)N * 40 * 2 + 255) & ~(size_t)255));
  (void)ws_size; (void)n_in; (void)out_size;

  int gg128 = (N + 127) / 128;
  int nb = (N + 3) / 4;

  // phase0: ehist + all weight swizzles (independent leaves)
  k_phase0<<<NEB + 296, 256, 0, stream>>>(dst, cnt_bm, E, chunk, nbk,
                                          Wl0, Wr0, Wl1, Wr1, Wl2, Wr2,
                                          wswz0, wswz1, wswz2);
  // phase1: bucket scans + layer-0 GEMM (overlapped, independent)
  k_phase1<<<nbk + gg128, 256, 0, stream>>>(cnt_bm, locoff, bktot, nbk,
                                            x, wswz0, b0, gA, gB, N);
  // edge placement (with in-block top-scan)
  k_eplace2<<<NEB, 256, 0, stream>>>(src, dst, bktot, locoff, bedge, bbase,
                                     row_ptr, E, chunk, nbk, N);
  k_bcsr2<<<nbk, 256, 0, stream>>>(bedge, bbase, row_ptr, col, N);

  // layer-0 aggregation (split — proven optimal)
  agg128b<<<nb, 256, 0, stream>>>(gA, gB, row_ptr, col, hC, N);
  // layer-1 GEMM (reuses gA/gB as outputs; they are dead after agg#1)
  gemm128_mfma<<<gg128, 256, 0, stream>>>(hC, wswz1, b1, gA, gB, N);
  // layer-1 agg + layer-2 gemm40 (fused; kept — measured ~-3us vs split)
  k_aggemm40<<<(N + 63) / 64, 256, 0, stream>>>(gA, gB, row_ptr, col,
                                                wswz2, b2, tlb, tr, N);
  // final aggregation + log_softmax
  agg40_lsm<<<nb, 256, 0, stream>>>(tlb, tr, row_ptr, col, (float*)d_out, N);
}